// Round 7
// baseline (371.095 us; speedup 1.0000x reference)
//
#include <hip/hip_runtime.h>
#include <math.h>

#define Bb 4
#define Ss 2048
#define Ee 1024
#define Hh 16
#define Dd 64
#define HD (Hh * Dd)  // 1024

typedef __attribute__((ext_vector_type(8))) _Float16 f16x8;   // 8 fp16 (4 VGPRs)
typedef __attribute__((ext_vector_type(4))) _Float16 f16x4;   // 4 fp16 (2 VGPRs)
typedef __attribute__((ext_vector_type(2))) _Float16 f16x2;
typedef __attribute__((ext_vector_type(4))) float f32x4;      // MFMA C/D

// async global->LDS, 16B per lane; LDS dest = wave-uniform base + lane*16
__device__ __forceinline__ void gl_lds16(const void* g, void* l) {
  __builtin_amdgcn_global_load_lds(
      (const __attribute__((address_space(1))) unsigned int*)g,
      (__attribute__((address_space(3))) unsigned int*)l, 16, 0, 0);
}

// packed f32x2 -> f16x2 (v_cvt_pkrtz_f16_f32)
__device__ __forceinline__ f16x2 pkrtz(float a, float b) {
  return __builtin_bit_cast(f16x2, __builtin_amdgcn_cvt_pkrtz(a, b));
}

// ---------------------------------------------------------------------------
// fused prep v2: grid-stride (R7). 35840 one-float4 blocks -> 3072 blocks:
// 2048 cvt blocks x ~9.5 float4/thread + 1024 mask blocks x 64 ballot-iters
// per wave. Same outputs as v1; removes per-block scheduling overhead and
// gives waves enough work to pipeline loads.
// ---------------------------------------------------------------------------
#define CVTB 2048
#define MSKB 1024
__global__ __launch_bounds__(256) void prep_all(const float* __restrict__ q,
                                                const float* __restrict__ h,
                                                const float* __restrict__ wq,
                                                const float* __restrict__ wk,
                                                const float* __restrict__ wv,
                                                _Float16* __restrict__ qf,
                                                _Float16* __restrict__ hf,
                                                _Float16* __restrict__ wqf,
                                                _Float16* __restrict__ wkf,
                                                _Float16* __restrict__ wvf,
                                                const int* __restrict__ mask,
                                                unsigned long long* __restrict__ pm) {
  if (blockIdx.x < CVTB) {
    const int QH = (Bb * Ss * Ee) / 4;       // 2M float4
    const int WM = (HD * Ee) / 4;            // 256K float4
    const int TOT = 2 * QH + 3 * WM;         // 4,980,736 float4
    for (int i = blockIdx.x * 256 + threadIdx.x; i < TOT; i += CVTB * 256) {
      const float* src;
      _Float16* dst;
      int off;
      if (i < QH)                   { src = q;  dst = qf;  off = i; }
      else if (i < 2 * QH)          { src = h;  dst = hf;  off = i - QH; }
      else if (i < 2 * QH + WM)     { src = wq; dst = wqf; off = i - 2 * QH; }
      else if (i < 2 * QH + 2 * WM) { src = wk; dst = wkf; off = i - 2 * QH - WM; }
      else                          { src = wv; dst = wvf; off = i - 2 * QH - 2 * WM; }
      float4 v = ((const float4*)src)[off];
      f16x4 o;
      o.x = (_Float16)v.x; o.y = (_Float16)v.y;
      o.z = (_Float16)v.z; o.w = (_Float16)v.w;
      *(f16x4*)(dst + 4 * (size_t)off) = o;
    }
  } else {
    // 1024 blocks x 4 waves = 4096 waves; 262,144 u64 words total -> 64/wave.
    const int wgid = (blockIdx.x - CVTB) * 4 + (threadIdx.x >> 6);  // 0..4095
    const int lane = threadIdx.x & 63;
    const int NW = (Bb * Ss * Ss) / 64;  // 262,144 words
#pragma unroll 4
    for (int w = wgid; w < NW; w += MSKB * 4) {
      unsigned long long bits = __ballot(mask[(size_t)w * 64 + lane] != 0);
      if (lane == 0) pm[w] = bits;
    }
  }
}

// ---------------------------------------------------------------------------
// Grouped QKV projection v4 (R7): faithful m97 single-buffer structure.
// 128x128 tile, BK=64, 256 thr = 4 waves each owning 64x64 (acc[4][4],
// 8 ds_read : 16 MFMA per s-phase). SINGLE 32KB LDS buffer ->
// ~4 blocks/CU co-resident; inter-block TLP hides the vmcnt(0) stage drain
// (m114/m97 mechanism). R6's 64KB dbuf halved occupancy and lost exactly
// what the pipeline gained -- reverted.
// For seg==2 (V) the epilogue writes TRANSPOSED directly to Vt.
// ---------------------------------------------------------------------------
__global__ __launch_bounds__(256, 3) void proj_qkv(const _Float16* __restrict__ qf,
                                                   const _Float16* __restrict__ hf,
                                                   const _Float16* __restrict__ Wqf,
                                                   const _Float16* __restrict__ Wkf,
                                                   const _Float16* __restrict__ Wvf,
                                                   _Float16* __restrict__ Qb,
                                                   _Float16* __restrict__ Kb,
                                                   _Float16* __restrict__ Vt) {
  __shared__ _Float16 As[128 * 64];  // 16 KB
  __shared__ _Float16 Bs[128 * 64];  // 16 KB
  const int seg = blockIdx.y;
  const _Float16* A = (seg == 0) ? qf : hf;
  const _Float16* W = (seg == 0) ? Wqf : ((seg == 1) ? Wkf : Wvf);
  const float scale = (seg == 0) ? 0.18033688011112042f : 1.0f;  // 0.125*log2(e)

  // lid = xcd + 8*m: nt fastest (m&7) -> 8 consecutive per-XCD blocks share
  // one A stripe (L2-hit) while W panel (2MB) stays resident.
  const int lid = blockIdx.x;
  const int xcd = lid & 7, m = lid >> 3;
  const int stripe = xcd + 8 * (m >> 3);   // 0..63
  const int nt = m & 7;                    // 0..7
  const int bm = stripe * 128, bn = nt * 128;

  const int tid = threadIdx.x;
  const int wv = tid >> 6, lane = tid & 63;
  const int quad = lane >> 4, l16 = lane & 15;
  const int wr = wv >> 1, wc = wv & 1;   // 2x2 waves of 64x64

  auto stage = [&](int k0) {
#pragma unroll
    for (int i = 0; i < 4; ++i) {
      int cb = wv * 64 + i * 256;          // wave-uniform physical chunk base
      int c = cb + lane;                   // physical chunk 0..1023
      int row = c >> 3;                    // 0..127
      int l = (c & 7) ^ (row & 7);         // logical chunk (XOR swizzle)
      gl_lds16(A + (size_t)(bm + row) * Ee + k0 + l * 8,
               (char*)&As[0] + (size_t)cb * 16);
    }
#pragma unroll
    for (int i = 0; i < 4; ++i) {
      int cb = wv * 64 + i * 256;
      int c = cb + lane;
      int row = c >> 3;
      int l = (c & 7) ^ (row & 7);
      gl_lds16(W + (size_t)(bn + row) * Ee + k0 + l * 8,
               (char*)&Bs[0] + (size_t)cb * 16);
    }
  };

  f32x4 acc[4][4];
#pragma unroll
  for (int i = 0; i < 4; ++i)
#pragma unroll
    for (int j = 0; j < 4; ++j) acc[i][j] = (f32x4){0.f, 0.f, 0.f, 0.f};

  const int NT = Ee / 64;  // 16
  for (int it = 0; it < NT; ++it) {
    stage(it * 64);
    // all 32 gl_lds of this block landed -> tile visible to every wave
    asm volatile("s_waitcnt vmcnt(0)\n\ts_barrier" ::: "memory");
#pragma unroll
    for (int s = 0; s < 2; ++s) {
      f16x8 af[4], bf[4];
#pragma unroll
      for (int i = 0; i < 4; ++i) {
        int row = wr * 64 + i * 16 + l16;
        int l = s * 4 + quad;
        af[i] = *(const f16x8*)&As[row * 64 + ((l ^ (row & 7)) << 3)];
      }
#pragma unroll
      for (int j = 0; j < 4; ++j) {
        int row = wc * 64 + j * 16 + l16;
        int l = s * 4 + quad;
        bf[j] = *(const f16x8*)&Bs[row * 64 + ((l ^ (row & 7)) << 3)];
      }
#pragma unroll
      for (int i = 0; i < 4; ++i)
#pragma unroll
        for (int j = 0; j < 4; ++j)
          acc[i][j] = __builtin_amdgcn_mfma_f32_16x16x32_f16(af[i], bf[j], acc[i][j], 0, 0, 0);
    }
    // all waves done READING before next stage overwrites (lgkm drained;
    // no vmem outstanding here so no hidden vmcnt cost)
    asm volatile("s_waitcnt lgkmcnt(0)\n\ts_barrier" ::: "memory");
  }

  if (seg < 2) {
    _Float16* Y = (seg == 0) ? Qb : Kb;
#pragma unroll
    for (int i = 0; i < 4; ++i)
#pragma unroll
      for (int j = 0; j < 4; ++j)
#pragma unroll
        for (int reg = 0; reg < 4; ++reg) {
          int row = bm + wr * 64 + i * 16 + quad * 4 + reg;
          int col = bn + wc * 64 + j * 16 + l16;
          Y[(size_t)row * HD + col] = (_Float16)(acc[i][j][reg] * scale);
        }
  } else {
    // V: transposed store. acc[i][j][0..3] = rows s0..s0+3 at fixed col ->
    // 4 consecutive Vt elements along s -> one 8B store.
    const int bvt = bm >> 11;            // batch (128-row tile never crosses)
    const int sbase = (bm & 2047) + wr * 64;
#pragma unroll
    for (int i = 0; i < 4; ++i)
#pragma unroll
      for (int j = 0; j < 4; ++j) {
        const int s0 = sbase + i * 16 + quad * 4;
        const int col = bn + wc * 64 + j * 16 + l16;
        f16x2 lo = pkrtz(acc[i][j][0], acc[i][j][1]);
        f16x2 hi = pkrtz(acc[i][j][2], acc[i][j][3]);
        f16x4 val = __builtin_shufflevector(lo, hi, 0, 1, 2, 3);
        *(f16x4*)(Vt + ((size_t)bvt * HD + col) * Ss + s0) = val;
      }
  }
}

// ---------------------------------------------------------------------------
// MFMA attention v8 (kept: 129us, FETCH ~34MB = ideal, issue-bound).
// ---------------------------------------------------------------------------
__global__ __launch_bounds__(256) void attn_mfma8(const _Float16* __restrict__ Qb,
                                                  const _Float16* __restrict__ Kb,
                                                  const _Float16* __restrict__ Vt,
                                                  const unsigned long long* __restrict__ pm,
                                                  float* __restrict__ out) {
  // decode: xcd = gid&7; m = gid>>3 = bq + 16*ph; (b,h) = xcd + 8*ph
  const int gid = blockIdx.x;          // 0..1023
  const int xcd = gid & 7, m = gid >> 3;
  const int bq = m & 15;               // q-tile within (b,h)
  const int p  = xcd + 8 * (m >> 4);   // 0..63 = (b,h) pair
  const int h  = p & 15;
  const int b  = p >> 4;
  const int tid  = threadIdx.x;
  const int wv   = tid >> 6;
  const int lane = tid & 63;
  const int quad = lane >> 4;
  const int l16  = lane & 15;

  __shared__ _Float16 Ks[64][64];   // 8 KB, XOR-swizzled chunks
  __shared__ _Float16 Vs[64][64];   // 8 KB, [d][k], XOR-swizzled chunks

  // Q fragments for both 16-row groups (hoisted from global)
  const int q0g = bq * 128 + wv * 32;
  f16x8 qf[2][2];
#pragma unroll
  for (int g = 0; g < 2; ++g) {
    const _Float16* qrow = Qb + ((size_t)b * Ss + q0g + g * 16 + l16) * HD + h * Dd;
    qf[g][0] = *(const f16x8*)(qrow + quad * 8);
    qf[g][1] = *(const f16x8*)(qrow + 32 + quad * 8);
  }

  // staging coords + write-side swizzle (16B chunk lc -> lc ^ swzr)
  const int r = tid >> 2, c = (tid & 3) << 4;
  const int swzr = (r & 7) ^ ((r & 4) >> 2);
  const int pw0 = ((c >> 3) ^ swzr) << 3;   // f16 offset of even chunk
  const int pw1 = pw0 ^ 8;                  // odd chunk: (lc^1)^swzr
  // read-side swizzle: fragment rows are sub*16+l16 / dt*16+l16
  const int swzl = (l16 & 7) ^ ((l16 & 4) >> 2);

  const _Float16* kbase = Kb + ((size_t)b * Ss + r) * HD + h * Dd + c;
  const _Float16* vbase = Vt + (((size_t)b * Hh + h) * Dd + r) * Ss + c;

  const unsigned long long* pmrow0 = pm + ((size_t)b * Ss + q0g + l16) * (Ss >> 6);
  const size_t pmg = (size_t)16 * (Ss >> 6);  // row offset for group 1

  f32x4 O[2][4];
#pragma unroll
  for (int g = 0; g < 2; ++g)
#pragma unroll
    for (int dt = 0; dt < 4; ++dt) O[g][dt] = (f32x4){0.f, 0.f, 0.f, 0.f};
  float lsum[2] = {0.f, 0.f};
  const f16x2 one2 = {(_Float16)1.0f, (_Float16)1.0f};
  const f32x4 zero4 = (f32x4){0.f, 0.f, 0.f, 0.f};

  f16x8 ka = *(const f16x8*)kbase;
  f16x8 kb2 = *(const f16x8*)(kbase + 8);
  f16x8 va = *(const f16x8*)vbase;
  f16x8 vb2 = *(const f16x8*)(vbase + 8);
  // mask prefetch (INVERTED: bit set = keep)
  unsigned long long mqn0 = ~pmrow0[0];
  unsigned long long mqn1 = ~pmrow0[pmg];

  for (int kt = 0; kt < Ss; kt += 64) {
    // B1: write-after-read hazard is LDS-only -> lgkm drain suffices; the
    // in-flight global/mask prefetch is NOT drained here.
    asm volatile("s_waitcnt lgkmcnt(0)\n\ts_barrier" ::: "memory");
    *(f16x8*)&Ks[r][pw0] = ka;
    *(f16x8*)&Ks[r][pw1] = kb2;
    *(f16x8*)&Vs[r][pw0] = va;
    *(f16x8*)&Vs[r][pw1] = vb2;
    const unsigned long long mq0 = mqn0, mq1 = mqn1;
    {
      const int ktn = (kt + 64) & (Ss - 1);
      ka  = *(const f16x8*)(kbase + (size_t)ktn * HD);
      kb2 = *(const f16x8*)(kbase + (size_t)ktn * HD + 8);
      va  = *(const f16x8*)(vbase + ktn);
      vb2 = *(const f16x8*)(vbase + ktn + 8);
      const int itn = (ktn >> 6);
      mqn0 = ~pmrow0[itn];
      mqn1 = ~pmrow0[pmg + itn];
    }
    // B2: read-after-write; ds_writes drained, globals stay in flight.
    asm volatile("s_waitcnt lgkmcnt(0)\n\ts_barrier" ::: "memory");

    // ---- K fragments once; S^T for both q-groups (C of first MFMA = zero) ----
    f32x4 c4[2][4];
    __builtin_amdgcn_s_setprio(1);
#pragma unroll
    for (int sub = 0; sub < 4; ++sub) {
      const _Float16* krow = &Ks[sub * 16 + l16][0];
      const int off0 = (quad ^ swzl) << 3;
      f16x8 k0 = *(const f16x8*)(krow + off0);
      f16x8 k1 = *(const f16x8*)(krow + (off0 ^ 32));
#pragma unroll
      for (int g = 0; g < 2; ++g) {
        c4[g][sub] = __builtin_amdgcn_mfma_f32_16x16x32_f16(k0, qf[g][0], zero4, 0, 0, 0);
        c4[g][sub] = __builtin_amdgcn_mfma_f32_16x16x32_f16(k1, qf[g][1], c4[g][sub], 0, 0, 0);
      }
    }
    __builtin_amdgcn_s_setprio(0);

    // ---- softmax: exp2 then zero via keep-mask; lsum via fdot2 ----
    f16x4 pf[2][4];
#pragma unroll
    for (int g = 0; g < 2; ++g) {
      const unsigned long long mqs = (g ? mq1 : mq0) >> (quad * 4);
      const unsigned kw0 = (unsigned)mqs;          // keep-bits 0..31
      const unsigned kw1 = (unsigned)(mqs >> 32);  // keep-bits 32..63
#pragma unroll
      for (int sub = 0; sub < 4; ++sub) {
        const unsigned word = (sub < 2) ? kw0 : kw1;
        float p[4];
#pragma unroll
        for (int reg = 0; reg < 4; ++reg) {
          const int pos = (sub & 1) * 16 + reg;
          const unsigned keep = (unsigned)(((int)(word << (31 - pos))) >> 31);
          float e = __builtin_amdgcn_exp2f(c4[g][sub][reg]);
          p[reg] = __builtin_bit_cast(float,
                     __builtin_bit_cast(unsigned, e) & keep);
        }
        f16x2 lo = pkrtz(p[0], p[1]);
        f16x2 hi = pkrtz(p[2], p[3]);
#if __has_builtin(__builtin_amdgcn_fdot2)
        lsum[g] = __builtin_amdgcn_fdot2(lo, one2, lsum[g], false);
        lsum[g] = __builtin_amdgcn_fdot2(hi, one2, lsum[g], false);
#else
        lsum[g] += (p[0] + p[1]) + (p[2] + p[3]);
#endif
        pf[g][sub] = __builtin_shufflevector(lo, hi, 0, 1, 2, 3);
      }
    }

    // ---- V fragments once; PV for both q-groups ----
    __builtin_amdgcn_s_setprio(1);
#pragma unroll
    for (int dt = 0; dt < 4; ++dt) {
      const _Float16* vrow = &Vs[dt * 16 + l16][0];
#pragma unroll
      for (int sub = 0; sub < 4; ++sub) {
        f16x4 vf = *(const f16x4*)(vrow + ((((2 * sub + (quad >> 1)) ^ swzl) << 3) +
                                           ((quad & 1) << 2)));
#pragma unroll
        for (int g = 0; g < 2; ++g)
          O[g][dt] = __builtin_amdgcn_mfma_f32_16x16x16f16(vf, pf[g][sub], O[g][dt], 0, 0, 0);
      }
    }
    __builtin_amdgcn_s_setprio(0);
  }

#pragma unroll
  for (int g = 0; g < 2; ++g) {
    float ls = lsum[g];
    ls += __shfl_xor(ls, 16, 64);
    ls += __shfl_xor(ls, 32, 64);
    const float inv = 1.0f / ls;
    float* obase = out + ((size_t)b * Ss + q0g + g * 16 + l16) * HD + h * Dd;
#pragma unroll
    for (int dt = 0; dt < 4; ++dt) {
      float4 st;
      st.x = O[g][dt][0] * inv; st.y = O[g][dt][1] * inv;
      st.z = O[g][dt][2] * inv; st.w = O[g][dt][3] * inv;
      *(float4*)(obase + dt * 16 + quad * 4) = st;
    }
  }
}

extern "C" void kernel_launch(void* const* d_in, const int* in_sizes, int n_in,
                              void* d_out, int out_size, void* d_ws, size_t ws_size,
                              hipStream_t stream) {
  const float* q    = (const float*)d_in[0];
  const float* h    = (const float*)d_in[1];
  const int*   mask = (const int*)d_in[2];
  const float* Wq   = (const float*)d_in[3];
  const float* Wk   = (const float*)d_in[4];
  const float* Wv   = (const float*)d_in[5];
  float* out = (float*)d_out;

  char* ws = (char*)d_ws;
  const size_t MB = 1024 * 1024;
  _Float16* qf  = (_Float16*)(ws);
  _Float16* hf  = (_Float16*)(ws + 16 * MB);
  _Float16* Wqf = (_Float16*)(ws + 32 * MB);
  _Float16* Wkf = (_Float16*)(ws + 34 * MB);
  _Float16* Wvf = (_Float16*)(ws + 36 * MB);
  _Float16* Qb  = (_Float16*)(ws + 38 * MB);
  _Float16* Kb  = (_Float16*)(ws + 54 * MB);
  _Float16* Vt  = (_Float16*)(ws + 70 * MB);  // written directly by proj (V)
  unsigned long long* pm = (unsigned long long*)(ws + 86 * MB);

  prep_all<<<CVTB + MSKB, 256, 0, stream>>>(
      q, h, Wq, Wk, Wv, qf, hf, Wqf, Wkf, Wvf, mask, pm);

  proj_qkv<<<dim3(512, 3), 256, 0, stream>>>(qf, hf, Wqf, Wkf, Wvf, Qb, Kb, Vt);

  attn_mfma8<<<1024, 256, 0, stream>>>(Qb, Kb, Vt, pm, out);
}

// Round 8
// 342.290 us; speedup vs baseline: 1.0842x; 1.0842x over previous
//
#include <hip/hip_runtime.h>
#include <math.h>

#define Bb 4
#define Ss 2048
#define Ee 1024
#define Hh 16
#define Dd 64
#define HD (Hh * Dd)  // 1024

typedef __attribute__((ext_vector_type(8))) _Float16 f16x8;   // 8 fp16 (4 VGPRs)
typedef __attribute__((ext_vector_type(4))) _Float16 f16x4;   // 4 fp16 (2 VGPRs)
typedef __attribute__((ext_vector_type(2))) _Float16 f16x2;
typedef __attribute__((ext_vector_type(4))) float f32x4;      // MFMA C/D

// async global->LDS, 16B per lane; LDS dest = wave-uniform base + lane*16
__device__ __forceinline__ void gl_lds16(const void* g, void* l) {
  __builtin_amdgcn_global_load_lds(
      (const __attribute__((address_space(1))) unsigned int*)g,
      (__attribute__((address_space(3))) unsigned int*)l, 16, 0, 0);
}

// packed f32x2 -> f16x2 (v_cvt_pkrtz_f16_f32)
__device__ __forceinline__ f16x2 pkrtz(float a, float b) {
  return __builtin_bit_cast(f16x2, __builtin_amdgcn_cvt_pkrtz(a, b));
}

// ---------------------------------------------------------------------------
// fused prep (R0 version, ran in all best totals): fp32->fp16 for
// q,h,Wq,Wk,Wv + mask bit-pack, one launch.
// ---------------------------------------------------------------------------
#define CVT_BLOCKS 19456
__global__ __launch_bounds__(256) void prep_all(const float* __restrict__ q,
                                                const float* __restrict__ h,
                                                const float* __restrict__ wq,
                                                const float* __restrict__ wk,
                                                const float* __restrict__ wv,
                                                _Float16* __restrict__ qf,
                                                _Float16* __restrict__ hf,
                                                _Float16* __restrict__ wqf,
                                                _Float16* __restrict__ wkf,
                                                _Float16* __restrict__ wvf,
                                                const int* __restrict__ mask,
                                                unsigned long long* __restrict__ pm) {
  if (blockIdx.x < CVT_BLOCKS) {
    const int QH = (Bb * Ss * Ee) / 4;       // 2M float4
    const int WM = (HD * Ee) / 4;            // 256K float4
    int i = blockIdx.x * 256 + threadIdx.x;
    const float* src;
    _Float16* dst;
    int off;
    if (i < QH)                   { src = q;  dst = qf;  off = i; }
    else if (i < 2 * QH)          { src = h;  dst = hf;  off = i - QH; }
    else if (i < 2 * QH + WM)     { src = wq; dst = wqf; off = i - 2 * QH; }
    else if (i < 2 * QH + 2 * WM) { src = wk; dst = wkf; off = i - 2 * QH - WM; }
    else                          { src = wv; dst = wvf; off = i - 2 * QH - 2 * WM; }
    float4 v = ((const float4*)src)[off];
    f16x4 o;
    o.x = (_Float16)v.x; o.y = (_Float16)v.y;
    o.z = (_Float16)v.z; o.w = (_Float16)v.w;
    *(f16x4*)(dst + 4 * (size_t)off) = o;
  } else {
    // 4 waves/block, each wave handles 16 rows of 64 ints (4 ballots of 64)
    const int bid = blockIdx.x - CVT_BLOCKS;
    const int wv = threadIdx.x >> 6, lane = threadIdx.x & 63;
    const size_t base = ((size_t)bid * 4 + wv) * 256;  // 4 u64-rows per wave
#pragma unroll
    for (int i = 0; i < 4; ++i) {
      unsigned long long bits = __ballot(mask[base + i * 64 + lane] != 0);
      if (lane == 0) pm[(base >> 6) + i] = bits;
    }
  }
}

// ---------------------------------------------------------------------------
// Grouped QKV projection (R8 = R5's measured-best structure, byte-for-byte,
// with only the epilogue swapped for the R6-verified fused-Vt store).
// 128x128 tile, 512 thr = 8 waves (2r x 4c of 64x32), BK=64 double-buffered
// (64 KB -> 2 blocks/CU), counted vmcnt(4) prefetch: tile it+1's 4 loads
// stay in flight across the barrier (the one technique with a large
// isolated measurement; R7's vmcnt(0) single-buffer lost ~30us vs this).
// seg==2 (V): epilogue writes TRANSPOSED directly to Vt (vtrans kernel
// eliminated, -32MB traffic, -1 launch).
// ---------------------------------------------------------------------------
__global__ __launch_bounds__(512, 4) void proj_qkv(const _Float16* __restrict__ qf,
                                                   const _Float16* __restrict__ hf,
                                                   const _Float16* __restrict__ Wqf,
                                                   const _Float16* __restrict__ Wkf,
                                                   const _Float16* __restrict__ Wvf,
                                                   _Float16* __restrict__ Qb,
                                                   _Float16* __restrict__ Kb,
                                                   _Float16* __restrict__ Vt) {
  __shared__ _Float16 As[2][128 * 64];  // 32 KB
  __shared__ _Float16 Bs[2][128 * 64];  // 32 KB
  const int seg = blockIdx.y;
  const _Float16* A = (seg == 0) ? qf : hf;
  const _Float16* W = (seg == 0) ? Wqf : ((seg == 1) ? Wkf : Wvf);
  const float scale = (seg == 0) ? 0.18033688011112042f : 1.0f;  // 0.125*log2(e)

  // R5 mapping: xcd = lid&7; concurrent per-XCD set = 4 stripes x 8 nt
  // (A 1MB + W 2MB = 3MB <= 4MB L2).
  const int lid = blockIdx.x;
  const int xcd = lid & 7, m = lid >> 3;           // m 0..63
  const int stripe = xcd + 8 * (m & 3) + 32 * (m >> 5);  // 0..63
  const int nt = (m >> 2) & 7;                     // 0..7
  const int bm = stripe * 128, bn = nt * 128;

  const int tid = threadIdx.x;
  const int wv = tid >> 6, lane = tid & 63;
  const int quad = lane >> 4, l16 = lane & 15;
  const int wr = wv >> 2, wc = wv & 3;   // 2 row-waves x 4 col-waves

  auto stage = [&](int buf, int k0) {
#pragma unroll
    for (int i = 0; i < 2; ++i) {
      int cb = wv * 64 + i * 512;          // wave-uniform physical chunk base
      int c = cb + lane;                   // physical chunk 0..1023
      int row = c >> 3;                    // 0..127
      int l = (c & 7) ^ (row & 7);         // logical chunk (XOR swizzle)
      gl_lds16(A + (size_t)(bm + row) * Ee + k0 + l * 8,
               (char*)&As[buf][0] + (size_t)cb * 16);
    }
#pragma unroll
    for (int i = 0; i < 2; ++i) {
      int cb = wv * 64 + i * 512;
      int c = cb + lane;
      int row = c >> 3;
      int l = (c & 7) ^ (row & 7);
      gl_lds16(W + (size_t)(bn + row) * Ee + k0 + l * 8,
               (char*)&Bs[buf][0] + (size_t)cb * 16);
    }
  };

  f32x4 acc[4][2];
#pragma unroll
  for (int i = 0; i < 4; ++i)
#pragma unroll
    for (int j = 0; j < 2; ++j) acc[i][j] = (f32x4){0.f, 0.f, 0.f, 0.f};

  stage(0, 0);
  const int NT = Ee / 64;  // 16
  for (int it = 0; it < NT; ++it) {
    const int buf = it & 1;
    if (it + 1 < NT) {
      stage(buf ^ 1, (it + 1) * 64);  // 4 loads stay in flight across barrier
      asm volatile("s_waitcnt vmcnt(4)\n\ts_barrier" ::: "memory");
    } else {
      asm volatile("s_waitcnt vmcnt(0)\n\ts_barrier" ::: "memory");
    }
#pragma unroll
    for (int s = 0; s < 2; ++s) {
      f16x8 af[4], bf[2];
#pragma unroll
      for (int i = 0; i < 4; ++i) {
        int row = wr * 64 + i * 16 + l16;
        int l = s * 4 + quad;
        af[i] = *(const f16x8*)&As[buf][row * 64 + ((l ^ (row & 7)) << 3)];
      }
#pragma unroll
      for (int j = 0; j < 2; ++j) {
        int row = wc * 32 + j * 16 + l16;
        int l = s * 4 + quad;
        bf[j] = *(const f16x8*)&Bs[buf][row * 64 + ((l ^ (row & 7)) << 3)];
      }
#pragma unroll
      for (int i = 0; i < 4; ++i)
#pragma unroll
        for (int j = 0; j < 2; ++j)
          acc[i][j] = __builtin_amdgcn_mfma_f32_16x16x32_f16(af[i], bf[j], acc[i][j], 0, 0, 0);
    }
    asm volatile("s_barrier" ::: "memory");
  }

  if (seg < 2) {
    _Float16* Y = (seg == 0) ? Qb : Kb;
#pragma unroll
    for (int i = 0; i < 4; ++i)
#pragma unroll
      for (int j = 0; j < 2; ++j)
#pragma unroll
        for (int reg = 0; reg < 4; ++reg) {
          int row = bm + wr * 64 + i * 16 + quad * 4 + reg;
          int col = bn + wc * 32 + j * 16 + l16;
          Y[(size_t)row * HD + col] = (_Float16)(acc[i][j][reg] * scale);
        }
  } else {
    // V: transposed store. acc[i][j][0..3] = rows s0..s0+3 at fixed col ->
    // 4 consecutive Vt elements along s -> one 8B store (R6-verified).
    const int bvt = bm >> 11;            // batch (128-row tile never crosses)
    const int sbase = (bm & 2047) + wr * 64;
#pragma unroll
    for (int i = 0; i < 4; ++i)
#pragma unroll
      for (int j = 0; j < 2; ++j) {
        const int s0 = sbase + i * 16 + quad * 4;
        const int col = bn + wc * 32 + j * 16 + l16;
        f16x2 lo = pkrtz(acc[i][j][0], acc[i][j][1]);
        f16x2 hi = pkrtz(acc[i][j][2], acc[i][j][3]);
        f16x4 val = __builtin_shufflevector(lo, hi, 0, 1, 2, 3);
        *(f16x4*)(Vt + ((size_t)bvt * HD + col) * Ss + s0) = val;
      }
  }
}

// ---------------------------------------------------------------------------
// MFMA attention v8 (kept: ~128us, FETCH ~34MB = ideal, issue-bound;
// 1.08 PF effective = 43% of peak).
// ---------------------------------------------------------------------------
__global__ __launch_bounds__(256) void attn_mfma8(const _Float16* __restrict__ Qb,
                                                  const _Float16* __restrict__ Kb,
                                                  const _Float16* __restrict__ Vt,
                                                  const unsigned long long* __restrict__ pm,
                                                  float* __restrict__ out) {
  // decode: xcd = gid&7; m = gid>>3 = bq + 16*ph; (b,h) = xcd + 8*ph
  const int gid = blockIdx.x;          // 0..1023
  const int xcd = gid & 7, m = gid >> 3;
  const int bq = m & 15;               // q-tile within (b,h)
  const int p  = xcd + 8 * (m >> 4);   // 0..63 = (b,h) pair
  const int h  = p & 15;
  const int b  = p >> 4;
  const int tid  = threadIdx.x;
  const int wv   = tid >> 6;
  const int lane = tid & 63;
  const int quad = lane >> 4;
  const int l16  = lane & 15;

  __shared__ _Float16 Ks[64][64];   // 8 KB, XOR-swizzled chunks
  __shared__ _Float16 Vs[64][64];   // 8 KB, [d][k], XOR-swizzled chunks

  // Q fragments for both 16-row groups (hoisted from global)
  const int q0g = bq * 128 + wv * 32;
  f16x8 qf[2][2];
#pragma unroll
  for (int g = 0; g < 2; ++g) {
    const _Float16* qrow = Qb + ((size_t)b * Ss + q0g + g * 16 + l16) * HD + h * Dd;
    qf[g][0] = *(const f16x8*)(qrow + quad * 8);
    qf[g][1] = *(const f16x8*)(qrow + 32 + quad * 8);
  }

  // staging coords + write-side swizzle (16B chunk lc -> lc ^ swzr)
  const int r = tid >> 2, c = (tid & 3) << 4;
  const int swzr = (r & 7) ^ ((r & 4) >> 2);
  const int pw0 = ((c >> 3) ^ swzr) << 3;   // f16 offset of even chunk
  const int pw1 = pw0 ^ 8;                  // odd chunk: (lc^1)^swzr
  // read-side swizzle: fragment rows are sub*16+l16 / dt*16+l16
  const int swzl = (l16 & 7) ^ ((l16 & 4) >> 2);

  const _Float16* kbase = Kb + ((size_t)b * Ss + r) * HD + h * Dd + c;
  const _Float16* vbase = Vt + (((size_t)b * Hh + h) * Dd + r) * Ss + c;

  const unsigned long long* pmrow0 = pm + ((size_t)b * Ss + q0g + l16) * (Ss >> 6);
  const size_t pmg = (size_t)16 * (Ss >> 6);  // row offset for group 1

  f32x4 O[2][4];
#pragma unroll
  for (int g = 0; g < 2; ++g)
#pragma unroll
    for (int dt = 0; dt < 4; ++dt) O[g][dt] = (f32x4){0.f, 0.f, 0.f, 0.f};
  float lsum[2] = {0.f, 0.f};
  const f16x2 one2 = {(_Float16)1.0f, (_Float16)1.0f};
  const f32x4 zero4 = (f32x4){0.f, 0.f, 0.f, 0.f};

  f16x8 ka = *(const f16x8*)kbase;
  f16x8 kb2 = *(const f16x8*)(kbase + 8);
  f16x8 va = *(const f16x8*)vbase;
  f16x8 vb2 = *(const f16x8*)(vbase + 8);
  // mask prefetch (INVERTED: bit set = keep)
  unsigned long long mqn0 = ~pmrow0[0];
  unsigned long long mqn1 = ~pmrow0[pmg];

  for (int kt = 0; kt < Ss; kt += 64) {
    // B1: write-after-read hazard is LDS-only -> lgkm drain suffices; the
    // in-flight global/mask prefetch is NOT drained here.
    asm volatile("s_waitcnt lgkmcnt(0)\n\ts_barrier" ::: "memory");
    *(f16x8*)&Ks[r][pw0] = ka;
    *(f16x8*)&Ks[r][pw1] = kb2;
    *(f16x8*)&Vs[r][pw0] = va;
    *(f16x8*)&Vs[r][pw1] = vb2;
    const unsigned long long mq0 = mqn0, mq1 = mqn1;
    {
      const int ktn = (kt + 64) & (Ss - 1);
      ka  = *(const f16x8*)(kbase + (size_t)ktn * HD);
      kb2 = *(const f16x8*)(kbase + (size_t)ktn * HD + 8);
      va  = *(const f16x8*)(vbase + ktn);
      vb2 = *(const f16x8*)(vbase + ktn + 8);
      const int itn = (ktn >> 6);
      mqn0 = ~pmrow0[itn];
      mqn1 = ~pmrow0[pmg + itn];
    }
    // B2: read-after-write; ds_writes drained, globals stay in flight.
    asm volatile("s_waitcnt lgkmcnt(0)\n\ts_barrier" ::: "memory");

    // ---- K fragments once; S^T for both q-groups (C of first MFMA = zero) ----
    f32x4 c4[2][4];
    __builtin_amdgcn_s_setprio(1);
#pragma unroll
    for (int sub = 0; sub < 4; ++sub) {
      const _Float16* krow = &Ks[sub * 16 + l16][0];
      const int off0 = (quad ^ swzl) << 3;
      f16x8 k0 = *(const f16x8*)(krow + off0);
      f16x8 k1 = *(const f16x8*)(krow + (off0 ^ 32));
#pragma unroll
      for (int g = 0; g < 2; ++g) {
        c4[g][sub] = __builtin_amdgcn_mfma_f32_16x16x32_f16(k0, qf[g][0], zero4, 0, 0, 0);
        c4[g][sub] = __builtin_amdgcn_mfma_f32_16x16x32_f16(k1, qf[g][1], c4[g][sub], 0, 0, 0);
      }
    }
    __builtin_amdgcn_s_setprio(0);

    // ---- softmax: exp2 then zero via keep-mask; lsum via fdot2 ----
    f16x4 pf[2][4];
#pragma unroll
    for (int g = 0; g < 2; ++g) {
      const unsigned long long mqs = (g ? mq1 : mq0) >> (quad * 4);
      const unsigned kw0 = (unsigned)mqs;          // keep-bits 0..31
      const unsigned kw1 = (unsigned)(mqs >> 32);  // keep-bits 32..63
#pragma unroll
      for (int sub = 0; sub < 4; ++sub) {
        const unsigned word = (sub < 2) ? kw0 : kw1;
        float p[4];
#pragma unroll
        for (int reg = 0; reg < 4; ++reg) {
          const int pos = (sub & 1) * 16 + reg;
          const unsigned keep = (unsigned)(((int)(word << (31 - pos))) >> 31);
          float e = __builtin_amdgcn_exp2f(c4[g][sub][reg]);
          p[reg] = __builtin_bit_cast(float,
                     __builtin_bit_cast(unsigned, e) & keep);
        }
        f16x2 lo = pkrtz(p[0], p[1]);
        f16x2 hi = pkrtz(p[2], p[3]);
#if __has_builtin(__builtin_amdgcn_fdot2)
        lsum[g] = __builtin_amdgcn_fdot2(lo, one2, lsum[g], false);
        lsum[g] = __builtin_amdgcn_fdot2(hi, one2, lsum[g], false);
#else
        lsum[g] += (p[0] + p[1]) + (p[2] + p[3]);
#endif
        pf[g][sub] = __builtin_shufflevector(lo, hi, 0, 1, 2, 3);
      }
    }

    // ---- V fragments once; PV for both q-groups ----
    __builtin_amdgcn_s_setprio(1);
#pragma unroll
    for (int dt = 0; dt < 4; ++dt) {
      const _Float16* vrow = &Vs[dt * 16 + l16][0];
#pragma unroll
      for (int sub = 0; sub < 4; ++sub) {
        f16x4 vf = *(const f16x4*)(vrow + ((((2 * sub + (quad >> 1)) ^ swzl) << 3) +
                                           ((quad & 1) << 2)));
#pragma unroll
        for (int g = 0; g < 2; ++g)
          O[g][dt] = __builtin_amdgcn_mfma_f32_16x16x16f16(vf, pf[g][sub], O[g][dt], 0, 0, 0);
      }
    }
    __builtin_amdgcn_s_setprio(0);
  }

#pragma unroll
  for (int g = 0; g < 2; ++g) {
    float ls = lsum[g];
    ls += __shfl_xor(ls, 16, 64);
    ls += __shfl_xor(ls, 32, 64);
    const float inv = 1.0f / ls;
    float* obase = out + ((size_t)b * Ss + q0g + g * 16 + l16) * HD + h * Dd;
#pragma unroll
    for (int dt = 0; dt < 4; ++dt) {
      float4 st;
      st.x = O[g][dt][0] * inv; st.y = O[g][dt][1] * inv;
      st.z = O[g][dt][2] * inv; st.w = O[g][dt][3] * inv;
      *(float4*)(obase + dt * 16 + quad * 4) = st;
    }
  }
}

extern "C" void kernel_launch(void* const* d_in, const int* in_sizes, int n_in,
                              void* d_out, int out_size, void* d_ws, size_t ws_size,
                              hipStream_t stream) {
  const float* q    = (const float*)d_in[0];
  const float* h    = (const float*)d_in[1];
  const int*   mask = (const int*)d_in[2];
  const float* Wq   = (const float*)d_in[3];
  const float* Wk   = (const float*)d_in[4];
  const float* Wv   = (const float*)d_in[5];
  float* out = (float*)d_out;

  char* ws = (char*)d_ws;
  const size_t MB = 1024 * 1024;
  _Float16* qf  = (_Float16*)(ws);
  _Float16* hf  = (_Float16*)(ws + 16 * MB);
  _Float16* Wqf = (_Float16*)(ws + 32 * MB);
  _Float16* Wkf = (_Float16*)(ws + 34 * MB);
  _Float16* Wvf = (_Float16*)(ws + 36 * MB);
  _Float16* Qb  = (_Float16*)(ws + 38 * MB);
  _Float16* Kb  = (_Float16*)(ws + 54 * MB);
  _Float16* Vt  = (_Float16*)(ws + 70 * MB);  // written directly by proj (V)
  unsigned long long* pm = (unsigned long long*)(ws + 86 * MB);

  const int mask_blocks = (Bb * Ss * Ss) / 1024;  // 16384
  prep_all<<<CVT_BLOCKS + mask_blocks, 256, 0, stream>>>(
      q, h, Wq, Wk, Wv, qf, hf, Wqf, Wkf, Wvf, mask, pm);

  proj_qkv<<<dim3(512, 3), 512, 0, stream>>>(qf, hf, Wqf, Wkf, Wvf, Qb, Kb, Vt);

  attn_mfma8<<<1024, 256, 0, stream>>>(Qb, Kb, Vt, pm, out);
}